// Round 8
// baseline (524.313 us; speedup 1.0000x reference)
//
#include <hip/hip_runtime.h>
#include <hip/hip_bf16.h>
#include <stdint.h>

// CRF entity layer: B=64, T=512, H=768, K=32
//   1) gemm_pot: pot = x·W + b
//   2) phaseA: per-chunk (L=8) 32x32 composition maps, one chunk per wave.
//        LSE maps in linear space (f32, per-chunk max-normalized);
//        Viterbi maps in max-plus. Identity for dead chunks (t>=len).
//   3) phaseB: per-batch serial combine over 64 maps (DPP-tree apply,
//        LDS double-buffered staging) -> logZ[b], vb boundaries, last[b]
//   4) phaseC: per-chunk 7-step Viterbi recompute from vb -> va
//   5) bp_extract: bp[b][t][k] = argmax_j(va[t-1][j]+trans[j][k])
//   6) backtrace: log-depth composition scan -> preds; + seq score -> ll
//
// ws layout (bytes):
//   pot : 0         4MB (+4KB pad)
//   va  : 4198400   4MB (+4KB pad)
//   bp  : 8396800   1MB
//   logZ: 9445376   256B
//   last: 9445632   256B
//   maps_lse: 9445888   16MB  (4096 chunks x 1024 f32)
//   s_lse   : 26223104  16KB
//   maps_vit: 26239488  16MB
//   vb      : 43016704  512KB

#define TT 512
#define KK 32
#define HH 768
#define NB 64

#define WS_POT  0
#define WS_VA   4198400
#define WS_BP   8396800
#define WS_LOGZ 9445376
#define WS_LAST 9445632
#define WS_MLSE 9445888
#define WS_SLSE 26223104
#define WS_MVIT 26239488
#define WS_VB   43016704

// ---------------- cross-lane primitives (VALU-speed) ----------------
template <int CTRL>
__device__ __forceinline__ float dppx(float x) {
  return __int_as_float(__builtin_amdgcn_update_dpp(
      0, __float_as_int(x), CTRL, 0xF, 0xF, true));
}
// x[lane^16] via v_permlane16_swap (direction-agnostic xor trick)
__device__ __forceinline__ float xor16f(float x) {
  float d = x, s = x;
  asm volatile("v_permlane16_swap_b32 %0, %1" : "+v"(d), "+v"(s));
  return __uint_as_float(__float_as_uint(d) ^ __float_as_uint(s) ^ __float_as_uint(x));
}
// x[lane^32]
__device__ __forceinline__ float xor32f(float x) {
  float d = x, s = x;
  asm volatile("v_permlane32_swap_b32 %0, %1" : "+v"(d), "+v"(s));
  return __uint_as_float(__float_as_uint(d) ^ __float_as_uint(s) ^ __float_as_uint(x));
}

// Gray maps: gmap covers [0,16) with generators {1,2,7,8}; g5 adds 16.
__device__ __forceinline__ int gmap(int m) {
  return ((m & 1) ? 1 : 0) ^ ((m & 2) ? 2 : 0) ^ ((m & 4) ? 7 : 0) ^ ((m & 8) ? 8 : 0);
}
__device__ __forceinline__ int g5(int m) { return gmap(m & 15) ^ ((m & 16) ? 16 : 0); }

// A[m] = a_from_lane(k ^ gmap(m)), m=0..15
#define REPL_TREE(A)                                            \
  A[1] = dppx<0xB1>(A[0]);                                      \
  _Pragma("unroll") for (int p = 0; p < 2; ++p) A[2 + p] = dppx<0x4E>(A[p]);  \
  _Pragma("unroll") for (int p = 0; p < 4; ++p) A[4 + p] = dppx<0x141>(A[p]); \
  _Pragma("unroll") for (int p = 0; p < 8; ++p) A[8 + p] = dppx<0x128>(A[p]);

// A[m] = a_from_lane(k ^ g5(m)), m=0..31  (within each 32-half)
#define REPL_TREE32(A)                                          \
  REPL_TREE(A)                                                  \
  _Pragma("unroll") for (int p = 0; p < 16; ++p) A[16 + p] = xor16f(A[p]);

__device__ __forceinline__ float redmax32(float v) {
  v = fmaxf(v, dppx<0xB1>(v));
  v = fmaxf(v, dppx<0x4E>(v));
  v = fmaxf(v, dppx<0x141>(v));
  v = fmaxf(v, dppx<0x128>(v));
  v = fmaxf(v, xor16f(v));
  return v;
}
__device__ __forceinline__ float redsum32(float v) {
  v += dppx<0xB1>(v);
  v += dppx<0x4E>(v);
  v += dppx<0x141>(v);
  v += dppx<0x128>(v);
  v += xor16f(v);
  return v;
}

// ---------------------------------------------------------------- GEMM ------
__global__ __launch_bounds__(256) void gemm_pot(const float* __restrict__ x,
                                                const float* __restrict__ W,
                                                const float* __restrict__ bias,
                                                float* __restrict__ pot) {
  __shared__ float4 xs4[64][16];
  __shared__ float4 wt4[32][16];
  const int tid = threadIdx.x;
  const int row0 = blockIdx.x * 64;
  const int cg = tid & 15;
  const int rg = tid >> 4;
  const int c0 = cg * 2;
  float acc[4][2] = {{0.f, 0.f}, {0.f, 0.f}, {0.f, 0.f}, {0.f, 0.f}};

  for (int h0 = 0; h0 < HH; h0 += 64) {
#pragma unroll
    for (int p = 0; p < 4; ++p) {
      const int fi = tid + p * 256;
      const int r = fi >> 4, s = fi & 15;
      const float4 v = *(const float4*)(&x[(size_t)(row0 + r) * HH + h0 + s * 4]);
      xs4[r][s ^ ((r >> 2) & 3)] = v;
    }
    {
      const int c = tid & 31;
      const int hb = (tid >> 5) * 8;
      float* wf = (float*)(&wt4[0][0]);
#pragma unroll
      for (int i2 = 0; i2 < 8; ++i2) {
        const int hh = hb + i2;
        const int slot = (hh >> 2) ^ ((c >> 1) & 15);
        wf[c * 64 + slot * 4 + (hh & 3)] = W[(size_t)(h0 + hh) * KK + c];
      }
    }
    __syncthreads();
#pragma unroll
    for (int s = 0; s < 16; ++s) {
      float4 xv[4];
#pragma unroll
      for (int i = 0; i < 4; ++i) xv[i] = xs4[rg * 4 + i][s ^ (rg & 3)];
      const float4 wv0 = wt4[c0][s ^ cg];
      const float4 wv1 = wt4[c0 + 1][s ^ cg];
#pragma unroll
      for (int i = 0; i < 4; ++i) {
        acc[i][0] += xv[i].x * wv0.x + xv[i].y * wv0.y + xv[i].z * wv0.z + xv[i].w * wv0.w;
        acc[i][1] += xv[i].x * wv1.x + xv[i].y * wv1.y + xv[i].z * wv1.z + xv[i].w * wv1.w;
      }
    }
    __syncthreads();
  }
#pragma unroll
  for (int i = 0; i < 4; ++i) {
    const int row = row0 + rg * 4 + i;
    float2 o = make_float2(acc[i][0] + bias[c0], acc[i][1] + bias[c0 + 1]);
    *(float2*)(&pot[(size_t)row * KK + c0]) = o;
  }
}

// --------------------------------------------------------------- phase A ----
// grid 2048 x 256: blocks [0,1024) LSE, [1024,2048) Viterbi. One chunk/wave.
// lane = j*2 + h: owns M[j][16h..16h+16). Partner half via quad_perm xor1.
__global__ __launch_bounds__(256) void phaseA(const float* __restrict__ pot,
                                              const int* __restrict__ lens,
                                              const float* __restrict__ trans,
                                              float* __restrict__ maps_lse,
                                              float* __restrict__ scale_lse,
                                              float* __restrict__ maps_vit) {
  __shared__ float E[1024];
  const int tid = threadIdx.x;
  const bool is_lse = (blockIdx.x < 1024);
  const int blk = is_lse ? blockIdx.x : blockIdx.x - 1024;
  const int b = blk >> 4;
  const int c = (blk & 15) * 4 + (tid >> 6);
  const int lane = tid & 63;
  const int j = lane >> 1, h = lane & 1;

#pragma unroll
  for (int q = 0; q < 4; ++q) {
    const float v = trans[tid + q * 256];
    E[tid + q * 256] = is_lse ? __expf(v) : v;
  }
  __syncthreads();

  const int len = lens[b];
  const int t0 = 8 * c + 1;
  const int t1 = min(8 * c + 8, len - 1);
  const size_t id = (size_t)b * 64 + c;
  float* outp = (is_lse ? maps_lse : maps_vit) + id * 1024 + (j * 32 + 16 * h);
  float M[16];

  if (t0 > t1) {                       // dead chunk -> identity map
#pragma unroll
    for (int i = 0; i < 16; ++i)
      M[i] = is_lse ? ((16 * h + i) == j ? 1.f : 0.f)
                    : ((16 * h + i) == j ? 0.f : -1e30f);
    if (is_lse && lane == 0) scale_lse[id] = 0.f;
  } else {
    const float4* Eb = (const float4*)E;
    // init M = step(t0)
    {
      const float4* p4 = (const float4*)(pot + ((size_t)b * TT + t0) * KK + 16 * h);
      float4 d0 = p4[0], d1 = p4[1], d2 = p4[2], d3 = p4[3];
      float dv[16] = {d0.x, d0.y, d0.z, d0.w, d1.x, d1.y, d1.z, d1.w,
                      d2.x, d2.y, d2.z, d2.w, d3.x, d3.y, d3.z, d3.w};
      if (is_lse) {
#pragma unroll
        for (int i = 0; i < 16; ++i) dv[i] = __expf(dv[i]);
      }
#pragma unroll
      for (int i = 0; i < 16; ++i) {
        const float e = E[j * 32 + 16 * h + i];
        M[i] = is_lse ? e * dv[i] : e + dv[i];
      }
    }
    for (int t = t0 + 1; t <= t1; ++t) {
      const float4* p4 = (const float4*)(pot + ((size_t)b * TT + t) * KK + 16 * h);
      float4 d0 = p4[0], d1 = p4[1], d2 = p4[2], d3 = p4[3];
      float dv[16] = {d0.x, d0.y, d0.z, d0.w, d1.x, d1.y, d1.z, d1.w,
                      d2.x, d2.y, d2.z, d2.w, d3.x, d3.y, d3.z, d3.w};
      float Mp[16];
#pragma unroll
      for (int i = 0; i < 16; ++i) Mp[i] = dppx<0xB1>(M[i]);   // partner half (lane^1)
      float acc[16];
#pragma unroll
      for (int i = 0; i < 16; ++i) acc[i] = is_lse ? 0.f : -1e30f;

#define ROWOP(mval, ridx)                                                     \
      {                                                                       \
        const float4 e0 = Eb[(ridx) * 8 + 4 * h + 0];                         \
        const float4 e1 = Eb[(ridx) * 8 + 4 * h + 1];                         \
        const float4 e2 = Eb[(ridx) * 8 + 4 * h + 2];                         \
        const float4 e3 = Eb[(ridx) * 8 + 4 * h + 3];                         \
        if (is_lse) {                                                         \
          acc[0] += (mval) * e0.x;  acc[1] += (mval) * e0.y;                  \
          acc[2] += (mval) * e0.z;  acc[3] += (mval) * e0.w;                  \
          acc[4] += (mval) * e1.x;  acc[5] += (mval) * e1.y;                  \
          acc[6] += (mval) * e1.z;  acc[7] += (mval) * e1.w;                  \
          acc[8] += (mval) * e2.x;  acc[9] += (mval) * e2.y;                  \
          acc[10] += (mval) * e2.z; acc[11] += (mval) * e2.w;                 \
          acc[12] += (mval) * e3.x; acc[13] += (mval) * e3.y;                 \
          acc[14] += (mval) * e3.z; acc[15] += (mval) * e3.w;                 \
        } else {                                                              \
          acc[0] = fmaxf(acc[0], (mval) + e0.x);  acc[1] = fmaxf(acc[1], (mval) + e0.y);  \
          acc[2] = fmaxf(acc[2], (mval) + e0.z);  acc[3] = fmaxf(acc[3], (mval) + e0.w);  \
          acc[4] = fmaxf(acc[4], (mval) + e1.x);  acc[5] = fmaxf(acc[5], (mval) + e1.y);  \
          acc[6] = fmaxf(acc[6], (mval) + e1.z);  acc[7] = fmaxf(acc[7], (mval) + e1.w);  \
          acc[8] = fmaxf(acc[8], (mval) + e2.x);  acc[9] = fmaxf(acc[9], (mval) + e2.y);  \
          acc[10] = fmaxf(acc[10], (mval) + e2.z); acc[11] = fmaxf(acc[11], (mval) + e2.w); \
          acc[12] = fmaxf(acc[12], (mval) + e3.x); acc[13] = fmaxf(acc[13], (mval) + e3.y); \
          acc[14] = fmaxf(acc[14], (mval) + e3.z); acc[15] = fmaxf(acc[15], (mval) + e3.w); \
        }                                                                     \
      }

#pragma unroll
      for (int i2 = 0; i2 < 16; ++i2) ROWOP(M[i2], 16 * h + i2)        // own m's
#pragma unroll
      for (int i2 = 0; i2 < 16; ++i2) ROWOP(Mp[i2], 16 * (1 - h) + i2) // partner m's
#undef ROWOP
      if (is_lse) {
#pragma unroll
        for (int i = 0; i < 16; ++i) M[i] = acc[i] * __expf(dv[i]);
      } else {
#pragma unroll
        for (int i = 0; i < 16; ++i) M[i] = acc[i] + dv[i];
      }
    }
    if (is_lse) {                       // normalize map by its max entry
      float mx = M[0];
#pragma unroll
      for (int i = 1; i < 16; ++i) mx = fmaxf(mx, M[i]);
      mx = fmaxf(mx, dppx<0xB1>(mx));
      mx = fmaxf(mx, dppx<0x4E>(mx));
      mx = fmaxf(mx, dppx<0x141>(mx));
      mx = fmaxf(mx, dppx<0x128>(mx));
      mx = fmaxf(mx, xor16f(mx));
      mx = fmaxf(mx, xor32f(mx));
      const float inv = __builtin_amdgcn_rcpf(mx);
#pragma unroll
      for (int i = 0; i < 16; ++i) M[i] *= inv;
      if (lane == 0) scale_lse[id] = __logf(mx);
    }
  }
  float4* o4 = (float4*)outp;
#pragma unroll
  for (int q = 0; q < 4; ++q)
    o4[q] = make_float4(M[4 * q], M[4 * q + 1], M[4 * q + 2], M[4 * q + 3]);
}

// --------------------------------------------------------------- phase B ----
// grid 128 x 256: blocks [0,64) LSE -> logZ; [64,128) Viterbi -> vb, last.
// lanes<32 combine serially; tid>=64 double-buffer-stage the next 8 maps.
__global__ __launch_bounds__(256) void phaseB(const float* __restrict__ pot,
                                              const float* __restrict__ maps_lse,
                                              const float* __restrict__ scale_lse,
                                              const float* __restrict__ maps_vit,
                                              float* __restrict__ vb,
                                              float* __restrict__ logZ,
                                              int* __restrict__ last) {
  __shared__ float mbuf[2][8192];
  __shared__ float sscale;
  const int tid = threadIdx.x;
  const bool is_lse = (blockIdx.x < 64);
  const int b = is_lse ? blockIdx.x : blockIdx.x - 64;
  const float* maps = (is_lse ? maps_lse : maps_vit) + (size_t)b * 65536;

  {  // stage round 0
    const float4* src = (const float4*)maps;
    for (int q = tid; q < 2048; q += 256) ((float4*)mbuf[0])[q] = src[q];
  }
  if (is_lse && tid == 64) {           // total of per-chunk log-scales
    float s = 0.f;
#pragma unroll 8
    for (int cc = 0; cc < 64; ++cc) s += scale_lse[b * 64 + cc];
    sscale = s;
  }
  __syncthreads();

  const int k = tid;
  float aown = 0.f, alog = 0.f;
  int addr[32];
  if (tid < 32) {
#pragma unroll
    for (int m = 0; m < 32; ++m) addr[m] = ((k ^ g5(m)) << 5) + k;
    const float a0 = pot[(size_t)b * (TT * KK) + k];
    if (is_lse) {
      const float m0 = redmax32(a0);
      aown = __expf(a0 - m0);
      alog = m0;
    } else {
      aown = a0;
    }
  }

  for (int r = 0; r < 8; ++r) {
    if (r < 7 && tid >= 64) {
      const float4* src = (const float4*)(maps + (size_t)(r + 1) * 8192);
      float4* dst = (float4*)mbuf[(r + 1) & 1];
      for (int q = tid - 64; q < 2048; q += 192) dst[q] = src[q];
    }
    if (tid < 32) {
      const float* mb0 = mbuf[r & 1];
#pragma unroll 1
      for (int m2 = 0; m2 < 8; ++m2) {
        const float* mb = mb0 + m2 * 1024;
        const int cc = r * 8 + m2;
        if (!is_lse) vb[((size_t)b * 64 + cc) * 32 + k] = aown;
        float mv[32];
#pragma unroll
        for (int m = 0; m < 32; ++m) mv[m] = mb[addr[m]];
        float A[32];
        A[0] = aown;
        REPL_TREE32(A)
        if (is_lse) {
          float mxA = A[0];                       // norm by pre-state max (VALU only)
#pragma unroll
          for (int m = 1; m < 32; ++m) mxA = fmaxf(mxA, A[m]);
          float s0 = 0.f, s1 = 0.f, s2 = 0.f, s3 = 0.f;
#pragma unroll
          for (int p = 0; p < 8; ++p) {
            s0 += A[4 * p + 0] * mv[4 * p + 0];
            s1 += A[4 * p + 1] * mv[4 * p + 1];
            s2 += A[4 * p + 2] * mv[4 * p + 2];
            s3 += A[4 * p + 3] * mv[4 * p + 3];
          }
          aown = ((s0 + s1) + (s2 + s3)) * __builtin_amdgcn_rcpf(mxA);
          alog += __logf(mxA);
        } else {
          float s0 = -1e30f, s1 = -1e30f, s2 = -1e30f, s3 = -1e30f;
#pragma unroll
          for (int p = 0; p < 8; ++p) {
            s0 = fmaxf(s0, A[4 * p + 0] + mv[4 * p + 0]);
            s1 = fmaxf(s1, A[4 * p + 1] + mv[4 * p + 1]);
            s2 = fmaxf(s2, A[4 * p + 2] + mv[4 * p + 2]);
            s3 = fmaxf(s3, A[4 * p + 3] + mv[4 * p + 3]);
          }
          aown = fmaxf(fmaxf(s0, s1), fmaxf(s2, s3));
        }
      }
    }
    __syncthreads();
  }
  if (tid < 32) {
    if (is_lse) {
      const float ssum = redsum32(aown);
      if (k == 0) logZ[b] = alog + __logf(ssum) + sscale;
    } else {
      float v = aown;
      int idx = k;
#pragma unroll
      for (int mm = 16; mm >= 1; mm >>= 1) {
        const float vo = __shfl_xor(v, mm, 32);
        const int io = __shfl_xor(idx, mm, 32);
        if (vo > v || (vo == v && io < idx)) { v = vo; idx = io; }
      }
      if (k == 0) last[b] = idx;
    }
  }
}

// --------------------------------------------------------------- phase C ----
// grid 1024 x 256: one chunk per wave; 7-step Viterbi recompute from vb -> va.
__global__ __launch_bounds__(256) void phaseC(const float* __restrict__ pot,
                                              const int* __restrict__ lens,
                                              const float* __restrict__ trans,
                                              const float* __restrict__ vb,
                                              float* __restrict__ va) {
  const int tid = threadIdx.x;
  const int lane = tid & 63;
  const int k = lane & 31;
  const int jh = lane >> 5;
  const int id = blockIdx.x * 4 + (tid >> 6);
  const int b = id >> 6, c = id & 63;
  const int len = lens[b];
  float trx[16];
#pragma unroll
  for (int m = 0; m < 16; ++m)
    trx[m] = trans[((k ^ gmap(m) ^ (jh << 4)) << 5) + k];
  const float* pp = pot + (size_t)b * (TT * KK) + k;
  float a = vb[(size_t)id * 32 + k];
  float* vap = va + ((size_t)b * TT + 8 * c) * KK + k;
  if (lane < 32) vap[0] = a;
  float pb[7];
#pragma unroll
  for (int i = 0; i < 7; ++i) pb[i] = pp[(size_t)(8 * c + 1 + i) * KK];
#pragma unroll
  for (int s = 0; s < 7; ++s) {
    const int t = 8 * c + 1 + s;
    float A[16];
    const float u16 = xor16f(a);
    A[0] = jh ? u16 : a;
    REPL_TREE(A)
    float s_[16];
#pragma unroll
    for (int m = 0; m < 16; ++m) s_[m] = A[m] + trx[m];
    const float m0 = fmaxf(fmaxf(s_[0], s_[1]), fmaxf(s_[2], s_[3]));
    const float m1 = fmaxf(fmaxf(s_[4], s_[5]), fmaxf(s_[6], s_[7]));
    const float m2 = fmaxf(fmaxf(s_[8], s_[9]), fmaxf(s_[10], s_[11]));
    const float m3 = fmaxf(fmaxf(s_[12], s_[13]), fmaxf(s_[14], s_[15]));
    const float part = fmaxf(fmaxf(m0, m1), fmaxf(m2, m3));
    const float anew = fmaxf(part, xor32f(part)) + pb[s];
    a = (t < len) ? anew : a;
    if (lane < 32) vap[(size_t)(s + 1) * KK] = a;
  }
}

// ----------------------------------------------------------- bp extract -----
__global__ __launch_bounds__(256) void bp_extract(const float* __restrict__ va,
                                                  const float* __restrict__ trans,
                                                  unsigned char* __restrict__ bp) {
  const int b = blockIdx.x >> 3;
  const int tbase = (blockIdx.x & 7) * 64;
  const int k = threadIdx.x & 31;
  const int ts = threadIdx.x >> 5;
  float tr[32];
#pragma unroll
  for (int j = 0; j < 32; ++j) tr[j] = trans[j * KK + k];
#pragma unroll
  for (int it = 0; it < 8; ++it) {
    const int t = tbase + it * 8 + ts;
    if (t < 1) continue;
    const float* row = va + ((size_t)b * TT + (t - 1)) * KK;
    float best = row[0] + tr[0];
    int bi = 0;
#pragma unroll
    for (int j = 1; j < 32; ++j) {
      const float s = row[j] + tr[j];
      if (s > best) { best = s; bi = j; }
    }
    bp[((size_t)b * TT + t) * KK + k] = (unsigned char)bi;
  }
}

// ------------------------------------------------------------- backtrace ----
__global__ __launch_bounds__(256) void backtrace_kernel(
    const unsigned char* __restrict__ bp, const int* __restrict__ lens,
    const int* __restrict__ last, const float* __restrict__ pot,
    const int* __restrict__ y, const float* __restrict__ trans,
    const float* __restrict__ logZ, float* __restrict__ out) {
  __shared__ unsigned char Ls[32736];
  __shared__ unsigned char sA[512], sB[512];
  __shared__ float red[256];
  const int b = blockIdx.x, tid = threadIdx.x;
  const int len = lens[b];

  for (int i = tid; i < TT * KK; i += 256) {
    const int t = i >> 5, k = i & 31;
    Ls[i] = (t >= 1 && t < len) ? bp[((size_t)b * TT + t) * KK + k] : (unsigned char)k;
  }
  __syncthreads();

  int off_prev = 0, cnt = 512;
  for (int l = 1; l <= 9; ++l) {
    const int off = 32 * (1024 - (1024 >> l));
    const int n = cnt >> 1;
    for (int i = tid; i < n * 32; i += 256) {
      const int m = i >> 5, k = i & 31;
      const int inner = Ls[off_prev + (2 * m + 1) * 32 + k];
      Ls[off + i] = Ls[off_prev + (2 * m) * 32 + inner];
    }
    __syncthreads();
    off_prev = off;
    cnt = n;
  }

  if (tid == 0) sA[0] = (unsigned char)last[b];
  __syncthreads();

  unsigned char* cur = sA;
  unsigned char* nxt = sB;
  int c2 = 1;
  for (int l = 9; l >= 1; --l) {
    const int offm = 32 * (1024 - (1024 >> (l - 1)));
    for (int i = tid; i < c2; i += 256) {
      const unsigned char s = cur[i];
      nxt[2 * i + 1] = s;
      nxt[2 * i] = Ls[offm + (2 * i + 1) * 32 + s];
    }
    __syncthreads();
    unsigned char* tmp = cur; cur = nxt; nxt = tmp;
    c2 <<= 1;
  }

  for (int t = tid; t < TT; t += 256)
    out[NB + (size_t)b * TT + t] = (t < len) ? (float)cur[t] : 0.f;

  float acc = 0.f;
  for (int t = tid; t < TT; t += 256) {
    const int yt = y[b * TT + t];
    if (t < len) acc += pot[((size_t)b * TT + t) * KK + yt];
    if (t < len - 1) acc += trans[yt * KK + y[b * TT + t + 1]];
  }
  red[tid] = acc;
  __syncthreads();
  for (int s = 128; s >= 1; s >>= 1) {
    if (tid < s) red[tid] += red[tid + s];
    __syncthreads();
  }
  if (tid == 0) out[b] = red[0] - logZ[b];
}

// ------------------------------------------------------------------ launch --
extern "C" void kernel_launch(void* const* d_in, const int* in_sizes, int n_in,
                              void* d_out, int out_size, void* d_ws, size_t ws_size,
                              hipStream_t stream) {
  const float* x = (const float*)d_in[0];
  const int* y = (const int*)d_in[1];
  const int* lens = (const int*)d_in[2];
  const float* W = (const float*)d_in[3];
  const float* bias = (const float*)d_in[4];
  const float* trans = (const float*)d_in[5];
  float* out = (float*)d_out;
  char* ws = (char*)d_ws;
  float* pot = (float*)(ws + WS_POT);
  float* va = (float*)(ws + WS_VA);
  unsigned char* bp = (unsigned char*)(ws + WS_BP);
  float* logZ = (float*)(ws + WS_LOGZ);
  int* last = (int*)(ws + WS_LAST);
  float* maps_lse = (float*)(ws + WS_MLSE);
  float* s_lse = (float*)(ws + WS_SLSE);
  float* maps_vit = (float*)(ws + WS_MVIT);
  float* vbp = (float*)(ws + WS_VB);

  gemm_pot<<<512, 256, 0, stream>>>(x, W, bias, pot);
  phaseA<<<2048, 256, 0, stream>>>(pot, lens, trans, maps_lse, s_lse, maps_vit);
  phaseB<<<128, 256, 0, stream>>>(pot, maps_lse, s_lse, maps_vit, vbp, logZ, last);
  phaseC<<<1024, 256, 0, stream>>>(pot, lens, trans, vbp, va);
  bp_extract<<<512, 256, 0, stream>>>(va, trans, bp);
  backtrace_kernel<<<64, 256, 0, stream>>>(bp, lens, last, pot, y, trans, logZ, out);
}

// Round 9
// 478.897 us; speedup vs baseline: 1.0948x; 1.0948x over previous
//
#include <hip/hip_runtime.h>
#include <hip/hip_bf16.h>
#include <stdint.h>

// CRF entity layer: B=64, T=512, H=768, K=32
//   1) etab_prep: etab = exp(trans)
//   2) gemm_pot: pot = x·W + b ; potExp = exp(pot)  (potExp shares va region)
//   3) phaseA_lse / phaseA_vit: per-chunk (L=8) 32x32 maps, row-per-lane,
//        E via wave-uniform s_loads (no LDS, no cross-lane, ~110 VGPR)
//   4) phaseB: per-batch serial combine over 64 maps -> logZ, vb, last
//   5) phaseC: per-chunk 7-step Viterbi recompute from vb -> va
//   6) bp_extract + backtrace -> preds, ll
//
// ws layout (bytes):
//   pot    : 0         4MB (+4KB pad)
//   potExp : 4198400   4MB   } same region: potExp dies after phaseA,
//   va     : 4198400   4MB   } va born in phaseC
//   bp     : 8396800   1MB
//   logZ   : 9445376   256B
//   last   : 9445632   256B
//   maps_lse: 9445888  16MB  (4096 chunks x 1024 f32)
//   s_lse  : 26223104  16KB
//   maps_vit: 26239488 16MB
//   vb     : 43016704  512KB
//   etab   : 43540992  4KB

#define TT 512
#define KK 32
#define HH 768
#define NB 64

#define WS_POT  0
#define WS_VA   4198400
#define WS_BP   8396800
#define WS_LOGZ 9445376
#define WS_LAST 9445632
#define WS_MLSE 9445888
#define WS_SLSE 26223104
#define WS_MVIT 26239488
#define WS_VB   43016704
#define WS_ETAB 43540992

// ---------------- cross-lane primitives (VALU-speed) ----------------
template <int CTRL>
__device__ __forceinline__ float dppx(float x) {
  return __int_as_float(__builtin_amdgcn_update_dpp(
      0, __float_as_int(x), CTRL, 0xF, 0xF, true));
}
__device__ __forceinline__ float xor16f(float x) {
  float d = x, s = x;
  asm volatile("v_permlane16_swap_b32 %0, %1" : "+v"(d), "+v"(s));
  return __uint_as_float(__float_as_uint(d) ^ __float_as_uint(s) ^ __float_as_uint(x));
}
__device__ __forceinline__ float xor32f(float x) {
  float d = x, s = x;
  asm volatile("v_permlane32_swap_b32 %0, %1" : "+v"(d), "+v"(s));
  return __uint_as_float(__float_as_uint(d) ^ __float_as_uint(s) ^ __float_as_uint(x));
}
__device__ __forceinline__ int gmap(int m) {
  return ((m & 1) ? 1 : 0) ^ ((m & 2) ? 2 : 0) ^ ((m & 4) ? 7 : 0) ^ ((m & 8) ? 8 : 0);
}
__device__ __forceinline__ int g5(int m) { return gmap(m & 15) ^ ((m & 16) ? 16 : 0); }

#define REPL_TREE(A)                                            \
  A[1] = dppx<0xB1>(A[0]);                                      \
  _Pragma("unroll") for (int p = 0; p < 2; ++p) A[2 + p] = dppx<0x4E>(A[p]);  \
  _Pragma("unroll") for (int p = 0; p < 4; ++p) A[4 + p] = dppx<0x141>(A[p]); \
  _Pragma("unroll") for (int p = 0; p < 8; ++p) A[8 + p] = dppx<0x128>(A[p]);
#define REPL_TREE32(A)                                          \
  REPL_TREE(A)                                                  \
  _Pragma("unroll") for (int p = 0; p < 16; ++p) A[16 + p] = xor16f(A[p]);

__device__ __forceinline__ float redmax32(float v) {
  v = fmaxf(v, dppx<0xB1>(v));
  v = fmaxf(v, dppx<0x4E>(v));
  v = fmaxf(v, dppx<0x141>(v));
  v = fmaxf(v, dppx<0x128>(v));
  v = fmaxf(v, xor16f(v));
  return v;
}
__device__ __forceinline__ float redsum32(float v) {
  v += dppx<0xB1>(v);
  v += dppx<0x4E>(v);
  v += dppx<0x141>(v);
  v += dppx<0x128>(v);
  v += xor16f(v);
  return v;
}

// ------------------------------------------------------------ etab prep -----
__global__ __launch_bounds__(256) void etab_prep(const float* __restrict__ trans,
                                                 float* __restrict__ etab) {
  const int i = blockIdx.x * 256 + threadIdx.x;
  etab[i] = __expf(trans[i]);
}

// ---------------------------------------------------------------- GEMM ------
__global__ __launch_bounds__(256) void gemm_pot(const float* __restrict__ x,
                                                const float* __restrict__ W,
                                                const float* __restrict__ bias,
                                                float* __restrict__ pot,
                                                float* __restrict__ potExp) {
  __shared__ float4 xs4[64][16];
  __shared__ float4 wt4[32][16];
  const int tid = threadIdx.x;
  const int row0 = blockIdx.x * 64;
  const int cg = tid & 15;
  const int rg = tid >> 4;
  const int c0 = cg * 2;
  float acc[4][2] = {{0.f, 0.f}, {0.f, 0.f}, {0.f, 0.f}, {0.f, 0.f}};

  for (int h0 = 0; h0 < HH; h0 += 64) {
#pragma unroll
    for (int p = 0; p < 4; ++p) {
      const int fi = tid + p * 256;
      const int r = fi >> 4, s = fi & 15;
      const float4 v = *(const float4*)(&x[(size_t)(row0 + r) * HH + h0 + s * 4]);
      xs4[r][s ^ ((r >> 2) & 3)] = v;
    }
    {
      const int c = tid & 31;
      const int hb = (tid >> 5) * 8;
      float* wf = (float*)(&wt4[0][0]);
#pragma unroll
      for (int i2 = 0; i2 < 8; ++i2) {
        const int hh = hb + i2;
        const int slot = (hh >> 2) ^ ((c >> 1) & 15);
        wf[c * 64 + slot * 4 + (hh & 3)] = W[(size_t)(h0 + hh) * KK + c];
      }
    }
    __syncthreads();
#pragma unroll
    for (int s = 0; s < 16; ++s) {
      float4 xv[4];
#pragma unroll
      for (int i = 0; i < 4; ++i) xv[i] = xs4[rg * 4 + i][s ^ (rg & 3)];
      const float4 wv0 = wt4[c0][s ^ cg];
      const float4 wv1 = wt4[c0 + 1][s ^ cg];
#pragma unroll
      for (int i = 0; i < 4; ++i) {
        acc[i][0] += xv[i].x * wv0.x + xv[i].y * wv0.y + xv[i].z * wv0.z + xv[i].w * wv0.w;
        acc[i][1] += xv[i].x * wv1.x + xv[i].y * wv1.y + xv[i].z * wv1.z + xv[i].w * wv1.w;
      }
    }
    __syncthreads();
  }
#pragma unroll
  for (int i = 0; i < 4; ++i) {
    const int row = row0 + rg * 4 + i;
    float2 o = make_float2(acc[i][0] + bias[c0], acc[i][1] + bias[c0 + 1]);
    *(float2*)(&pot[(size_t)row * KK + c0]) = o;
    *(float2*)(&potExp[(size_t)row * KK + c0]) = make_float2(__expf(o.x), __expf(o.y));
  }
}

// ----------------------------------------------------------- phase A LSE ----
// grid 512 x 256: 8 chunks/block, one chunk per 32-lane half. Lane owns ROW j
// of the chunk map M (32 VGPR). E[m][k] is wave-uniform -> s_load + v_fmac.
__global__ __launch_bounds__(256, 4) void phaseA_lse(
    const float* __restrict__ potExp, const int* __restrict__ lens,
    const float* __restrict__ etab, float* __restrict__ maps,
    float* __restrict__ scale) {
  const int tid = threadIdx.x;
  const int id = blockIdx.x * 8 + (tid >> 5);
  const int j = tid & 31;
  const int b = id >> 6, c = id & 63;
  const int len = lens[b];
  const int t0 = 8 * c + 1;
  const int t1 = min(8 * c + 8, len - 1);
  float* outp = maps + (size_t)id * 1024 + j * 32;

  float M[32];
  if (t0 > t1) {                       // dead chunk -> identity
#pragma unroll
    for (int kk = 0; kk < 32; ++kk) M[kk] = (kk == j) ? 1.f : 0.f;
    if (j == 0) scale[id] = 0.f;
  } else {
    {  // init: M[k] = E[j][k] * dv[k]
      float er[32], dv[32];
      const float4* e4 = (const float4*)(etab + j * 32);
      const float4* d4 = (const float4*)(potExp + ((size_t)b * TT + t0) * KK);
#pragma unroll
      for (int q = 0; q < 8; ++q) {
        const float4 ev = e4[q], dvv = d4[q];
        er[4 * q] = ev.x; er[4 * q + 1] = ev.y; er[4 * q + 2] = ev.z; er[4 * q + 3] = ev.w;
        dv[4 * q] = dvv.x; dv[4 * q + 1] = dvv.y; dv[4 * q + 2] = dvv.z; dv[4 * q + 3] = dvv.w;
      }
#pragma unroll
      for (int kk = 0; kk < 32; ++kk) M[kk] = er[kk] * dv[kk];
    }
#pragma unroll 1
    for (int t = t0 + 1; t <= t1; ++t) {
      float dv[32];
      const float4* d4 = (const float4*)(potExp + ((size_t)b * TT + t) * KK);
#pragma unroll
      for (int q = 0; q < 8; ++q) {
        const float4 v = d4[q];
        dv[4 * q] = v.x; dv[4 * q + 1] = v.y; dv[4 * q + 2] = v.z; dv[4 * q + 3] = v.w;
      }
      float acc[32];
#pragma unroll
      for (int kk = 0; kk < 32; ++kk) acc[kk] = 0.f;
#pragma unroll
      for (int m = 0; m < 32; ++m) {
#pragma unroll
        for (int kk = 0; kk < 32; ++kk)
          acc[kk] = __builtin_fmaf(M[m], etab[m * 32 + kk], acc[kk]);  // E uniform -> SGPR
      }
#pragma unroll
      for (int kk = 0; kk < 32; ++kk) M[kk] = acc[kk] * dv[kk];
    }
    // normalize by map max
    float mx = M[0];
#pragma unroll
    for (int kk = 1; kk < 32; ++kk) mx = fmaxf(mx, M[kk]);
    mx = redmax32(mx);
    const float inv = __builtin_amdgcn_rcpf(mx);
#pragma unroll
    for (int kk = 0; kk < 32; ++kk) M[kk] *= inv;
    if (j == 0) scale[id] = __logf(mx);
  }
  float4* o4 = (float4*)outp;
#pragma unroll
  for (int q = 0; q < 8; ++q)
    o4[q] = make_float4(M[4 * q], M[4 * q + 1], M[4 * q + 2], M[4 * q + 3]);
}

// ----------------------------------------------------------- phase A VIT ----
__global__ __launch_bounds__(256, 4) void phaseA_vit(
    const float* __restrict__ pot, const int* __restrict__ lens,
    const float* __restrict__ trans, float* __restrict__ maps) {
  const int tid = threadIdx.x;
  const int id = blockIdx.x * 8 + (tid >> 5);
  const int j = tid & 31;
  const int b = id >> 6, c = id & 63;
  const int len = lens[b];
  const int t0 = 8 * c + 1;
  const int t1 = min(8 * c + 8, len - 1);
  float* outp = maps + (size_t)id * 1024 + j * 32;

  float M[32];
  if (t0 > t1) {
#pragma unroll
    for (int kk = 0; kk < 32; ++kk) M[kk] = (kk == j) ? 0.f : -1e30f;
  } else {
    {  // init: M[k] = trans[j][k] + dv[k]
      float er[32], dv[32];
      const float4* e4 = (const float4*)(trans + j * 32);
      const float4* d4 = (const float4*)(pot + ((size_t)b * TT + t0) * KK);
#pragma unroll
      for (int q = 0; q < 8; ++q) {
        const float4 ev = e4[q], dvv = d4[q];
        er[4 * q] = ev.x; er[4 * q + 1] = ev.y; er[4 * q + 2] = ev.z; er[4 * q + 3] = ev.w;
        dv[4 * q] = dvv.x; dv[4 * q + 1] = dvv.y; dv[4 * q + 2] = dvv.z; dv[4 * q + 3] = dvv.w;
      }
#pragma unroll
      for (int kk = 0; kk < 32; ++kk) M[kk] = er[kk] + dv[kk];
    }
#pragma unroll 1
    for (int t = t0 + 1; t <= t1; ++t) {
      float dv[32];
      const float4* d4 = (const float4*)(pot + ((size_t)b * TT + t) * KK);
#pragma unroll
      for (int q = 0; q < 8; ++q) {
        const float4 v = d4[q];
        dv[4 * q] = v.x; dv[4 * q + 1] = v.y; dv[4 * q + 2] = v.z; dv[4 * q + 3] = v.w;
      }
      float acc[32];
#pragma unroll
      for (int kk = 0; kk < 32; ++kk) acc[kk] = -1e30f;
#pragma unroll
      for (int m = 0; m < 32; m += 2) {
#pragma unroll
        for (int kk = 0; kk < 32; ++kk) {
          const float u = M[m] + trans[m * 32 + kk];          // uniform -> SGPR
          const float w = M[m + 1] + trans[(m + 1) * 32 + kk];
          acc[kk] = fmaxf(fmaxf(acc[kk], u), w);              // v_max3
        }
      }
#pragma unroll
      for (int kk = 0; kk < 32; ++kk) M[kk] = acc[kk] + dv[kk];
    }
  }
  float4* o4 = (float4*)outp;
#pragma unroll
  for (int q = 0; q < 8; ++q)
    o4[q] = make_float4(M[4 * q], M[4 * q + 1], M[4 * q + 2], M[4 * q + 3]);
}

// --------------------------------------------------------------- phase B ----
// grid 128 x 256: [0,64) LSE -> logZ; [64,128) Viterbi -> vb, last.
__global__ __launch_bounds__(256) void phaseB(const float* __restrict__ pot,
                                              const float* __restrict__ maps_lse,
                                              const float* __restrict__ scale_lse,
                                              const float* __restrict__ maps_vit,
                                              float* __restrict__ vb,
                                              float* __restrict__ logZ,
                                              int* __restrict__ last) {
  __shared__ float mbuf[2][8192];
  __shared__ float sscale;
  const int tid = threadIdx.x;
  const bool is_lse = (blockIdx.x < 64);
  const int b = is_lse ? blockIdx.x : blockIdx.x - 64;
  const float* maps = (is_lse ? maps_lse : maps_vit) + (size_t)b * 65536;

  {
    const float4* src = (const float4*)maps;
    for (int q = tid; q < 2048; q += 256) ((float4*)mbuf[0])[q] = src[q];
  }
  if (is_lse && tid == 64) {
    float s = 0.f;
#pragma unroll 8
    for (int cc = 0; cc < 64; ++cc) s += scale_lse[b * 64 + cc];
    sscale = s;
  }
  __syncthreads();

  const int k = tid;
  float aown = 0.f, alog = 0.f;
  int addr[32];
  if (tid < 32) {
#pragma unroll
    for (int m = 0; m < 32; ++m) addr[m] = ((k ^ g5(m)) << 5) + k;
    const float a0 = pot[(size_t)b * (TT * KK) + k];
    if (is_lse) {
      const float m0 = redmax32(a0);
      aown = __expf(a0 - m0);
      alog = m0;
    } else {
      aown = a0;
    }
  }

  for (int r = 0; r < 8; ++r) {
    if (r < 7 && tid >= 64) {
      const float4* src = (const float4*)(maps + (size_t)(r + 1) * 8192);
      float4* dst = (float4*)mbuf[(r + 1) & 1];
      for (int q = tid - 64; q < 2048; q += 192) dst[q] = src[q];
    }
    if (tid < 32) {
      const float* mb0 = mbuf[r & 1];
#pragma unroll 1
      for (int m2 = 0; m2 < 8; ++m2) {
        const float* mb = mb0 + m2 * 1024;
        const int cc = r * 8 + m2;
        if (!is_lse) vb[((size_t)b * 64 + cc) * 32 + k] = aown;
        float mv[32];
#pragma unroll
        for (int m = 0; m < 32; ++m) mv[m] = mb[addr[m]];
        float A[32];
        A[0] = aown;
        REPL_TREE32(A)
        if (is_lse) {
          float mxA = A[0];
#pragma unroll
          for (int m = 1; m < 32; ++m) mxA = fmaxf(mxA, A[m]);
          float s0 = 0.f, s1 = 0.f, s2 = 0.f, s3 = 0.f;
#pragma unroll
          for (int p = 0; p < 8; ++p) {
            s0 += A[4 * p + 0] * mv[4 * p + 0];
            s1 += A[4 * p + 1] * mv[4 * p + 1];
            s2 += A[4 * p + 2] * mv[4 * p + 2];
            s3 += A[4 * p + 3] * mv[4 * p + 3];
          }
          aown = ((s0 + s1) + (s2 + s3)) * __builtin_amdgcn_rcpf(mxA);
          alog += __logf(mxA);
        } else {
          float s0 = -1e30f, s1 = -1e30f, s2 = -1e30f, s3 = -1e30f;
#pragma unroll
          for (int p = 0; p < 8; ++p) {
            s0 = fmaxf(s0, A[4 * p + 0] + mv[4 * p + 0]);
            s1 = fmaxf(s1, A[4 * p + 1] + mv[4 * p + 1]);
            s2 = fmaxf(s2, A[4 * p + 2] + mv[4 * p + 2]);
            s3 = fmaxf(s3, A[4 * p + 3] + mv[4 * p + 3]);
          }
          aown = fmaxf(fmaxf(s0, s1), fmaxf(s2, s3));
        }
      }
    }
    __syncthreads();
  }
  if (tid < 32) {
    if (is_lse) {
      const float ssum = redsum32(aown);
      if (k == 0) logZ[b] = alog + __logf(ssum) + sscale;
    } else {
      float v = aown;
      int idx = k;
#pragma unroll
      for (int mm = 16; mm >= 1; mm >>= 1) {
        const float vo = __shfl_xor(v, mm, 32);
        const int io = __shfl_xor(idx, mm, 32);
        if (vo > v || (vo == v && io < idx)) { v = vo; idx = io; }
      }
      if (k == 0) last[b] = idx;
    }
  }
}

// --------------------------------------------------------------- phase C ----
__global__ __launch_bounds__(256) void phaseC(const float* __restrict__ pot,
                                              const int* __restrict__ lens,
                                              const float* __restrict__ trans,
                                              const float* __restrict__ vb,
                                              float* __restrict__ va) {
  const int tid = threadIdx.x;
  const int lane = tid & 63;
  const int k = lane & 31;
  const int jh = lane >> 5;
  const int id = blockIdx.x * 4 + (tid >> 6);
  const int b = id >> 6, c = id & 63;
  const int len = lens[b];
  float trx[16];
#pragma unroll
  for (int m = 0; m < 16; ++m)
    trx[m] = trans[((k ^ gmap(m) ^ (jh << 4)) << 5) + k];
  const float* pp = pot + (size_t)b * (TT * KK) + k;
  float a = vb[(size_t)id * 32 + k];
  float* vap = va + ((size_t)b * TT + 8 * c) * KK + k;
  if (lane < 32) vap[0] = a;
  float pb[7];
#pragma unroll
  for (int i = 0; i < 7; ++i) pb[i] = pp[(size_t)(8 * c + 1 + i) * KK];
#pragma unroll
  for (int s = 0; s < 7; ++s) {
    const int t = 8 * c + 1 + s;
    float A[16];
    const float u16 = xor16f(a);
    A[0] = jh ? u16 : a;
    REPL_TREE(A)
    float s_[16];
#pragma unroll
    for (int m = 0; m < 16; ++m) s_[m] = A[m] + trx[m];
    const float m0 = fmaxf(fmaxf(s_[0], s_[1]), fmaxf(s_[2], s_[3]));
    const float m1 = fmaxf(fmaxf(s_[4], s_[5]), fmaxf(s_[6], s_[7]));
    const float m2 = fmaxf(fmaxf(s_[8], s_[9]), fmaxf(s_[10], s_[11]));
    const float m3 = fmaxf(fmaxf(s_[12], s_[13]), fmaxf(s_[14], s_[15]));
    const float part = fmaxf(fmaxf(m0, m1), fmaxf(m2, m3));
    const float anew = fmaxf(part, xor32f(part)) + pb[s];
    a = (t < len) ? anew : a;
    if (lane < 32) vap[(size_t)(s + 1) * KK] = a;
  }
}

// ----------------------------------------------------------- bp extract -----
__global__ __launch_bounds__(256) void bp_extract(const float* __restrict__ va,
                                                  const float* __restrict__ trans,
                                                  unsigned char* __restrict__ bp) {
  const int b = blockIdx.x >> 3;
  const int tbase = (blockIdx.x & 7) * 64;
  const int k = threadIdx.x & 31;
  const int ts = threadIdx.x >> 5;
  float tr[32];
#pragma unroll
  for (int j = 0; j < 32; ++j) tr[j] = trans[j * KK + k];
#pragma unroll
  for (int it = 0; it < 8; ++it) {
    const int t = tbase + it * 8 + ts;
    if (t < 1) continue;
    const float* row = va + ((size_t)b * TT + (t - 1)) * KK;
    float best = row[0] + tr[0];
    int bi = 0;
#pragma unroll
    for (int j = 1; j < 32; ++j) {
      const float s = row[j] + tr[j];
      if (s > best) { best = s; bi = j; }
    }
    bp[((size_t)b * TT + t) * KK + k] = (unsigned char)bi;
  }
}

// ------------------------------------------------------------- backtrace ----
__global__ __launch_bounds__(256) void backtrace_kernel(
    const unsigned char* __restrict__ bp, const int* __restrict__ lens,
    const int* __restrict__ last, const float* __restrict__ pot,
    const int* __restrict__ y, const float* __restrict__ trans,
    const float* __restrict__ logZ, float* __restrict__ out) {
  __shared__ unsigned char Ls[32736];
  __shared__ unsigned char sA[512], sB[512];
  __shared__ float red[256];
  const int b = blockIdx.x, tid = threadIdx.x;
  const int len = lens[b];

  for (int i = tid; i < TT * KK; i += 256) {
    const int t = i >> 5, k = i & 31;
    Ls[i] = (t >= 1 && t < len) ? bp[((size_t)b * TT + t) * KK + k] : (unsigned char)k;
  }
  __syncthreads();

  int off_prev = 0, cnt = 512;
  for (int l = 1; l <= 9; ++l) {
    const int off = 32 * (1024 - (1024 >> l));
    const int n = cnt >> 1;
    for (int i = tid; i < n * 32; i += 256) {
      const int m = i >> 5, k = i & 31;
      const int inner = Ls[off_prev + (2 * m + 1) * 32 + k];
      Ls[off + i] = Ls[off_prev + (2 * m) * 32 + inner];
    }
    __syncthreads();
    off_prev = off;
    cnt = n;
  }

  if (tid == 0) sA[0] = (unsigned char)last[b];
  __syncthreads();

  unsigned char* cur = sA;
  unsigned char* nxt = sB;
  int c2 = 1;
  for (int l = 9; l >= 1; --l) {
    const int offm = 32 * (1024 - (1024 >> (l - 1)));
    for (int i = tid; i < c2; i += 256) {
      const unsigned char s = cur[i];
      nxt[2 * i + 1] = s;
      nxt[2 * i] = Ls[offm + (2 * i + 1) * 32 + s];
    }
    __syncthreads();
    unsigned char* tmp = cur; cur = nxt; nxt = tmp;
    c2 <<= 1;
  }

  for (int t = tid; t < TT; t += 256)
    out[NB + (size_t)b * TT + t] = (t < len) ? (float)cur[t] : 0.f;

  float acc = 0.f;
  for (int t = tid; t < TT; t += 256) {
    const int yt = y[b * TT + t];
    if (t < len) acc += pot[((size_t)b * TT + t) * KK + yt];
    if (t < len - 1) acc += trans[yt * KK + y[b * TT + t + 1]];
  }
  red[tid] = acc;
  __syncthreads();
  for (int s = 128; s >= 1; s >>= 1) {
    if (tid < s) red[tid] += red[tid + s];
    __syncthreads();
  }
  if (tid == 0) out[b] = red[0] - logZ[b];
}

// ------------------------------------------------------------------ launch --
extern "C" void kernel_launch(void* const* d_in, const int* in_sizes, int n_in,
                              void* d_out, int out_size, void* d_ws, size_t ws_size,
                              hipStream_t stream) {
  const float* x = (const float*)d_in[0];
  const int* y = (const int*)d_in[1];
  const int* lens = (const int*)d_in[2];
  const float* W = (const float*)d_in[3];
  const float* bias = (const float*)d_in[4];
  const float* trans = (const float*)d_in[5];
  float* out = (float*)d_out;
  char* ws = (char*)d_ws;
  float* pot = (float*)(ws + WS_POT);
  float* potExp = (float*)(ws + WS_VA);   // shares region with va (disjoint lifetime)
  float* va = (float*)(ws + WS_VA);
  unsigned char* bp = (unsigned char*)(ws + WS_BP);
  float* logZ = (float*)(ws + WS_LOGZ);
  int* last = (int*)(ws + WS_LAST);
  float* maps_lse = (float*)(ws + WS_MLSE);
  float* s_lse = (float*)(ws + WS_SLSE);
  float* maps_vit = (float*)(ws + WS_MVIT);
  float* vbp = (float*)(ws + WS_VB);
  float* etab = (float*)(ws + WS_ETAB);

  etab_prep<<<4, 256, 0, stream>>>(trans, etab);
  gemm_pot<<<512, 256, 0, stream>>>(x, W, bias, pot, potExp);
  phaseA_lse<<<512, 256, 0, stream>>>(potExp, lens, etab, maps_lse, s_lse);
  phaseA_vit<<<512, 256, 0, stream>>>(pot, lens, trans, maps_vit);
  phaseB<<<128, 256, 0, stream>>>(pot, maps_lse, s_lse, maps_vit, vbp, logZ, last);
  phaseC<<<1024, 256, 0, stream>>>(pot, lens, trans, vbp, va);
  bp_extract<<<512, 256, 0, stream>>>(va, trans, bp);
  backtrace_kernel<<<64, 256, 0, stream>>>(bp, lens, last, pot, y, trans, logZ, out);
}

// Round 10
// 196.258 us; speedup vs baseline: 2.6716x; 2.4401x over previous
//
#include <hip/hip_runtime.h>
#include <hip/hip_bf16.h>
#include <stdint.h>

// CRF entity layer: B=64, T=512, H=768, K=32
//   1) gemm_pot: pot = x·W + b
//   2) phaseA: per-chunk (L=8) 32x32 maps, ROW-PER-LANE (lane j owns map row),
//        E rows via uniform-address LDS broadcast float4 reads (no s_load trap,
//        no cross-lane). LSE linear-space (normalized) + Viterbi max-plus.
//   3) phaseB: per-batch serial combine over 64 maps -> logZ, vb, last
//   4) phaseC: per-chunk 8-step Viterbi recompute from vb; bp fused via
//        mask+ctz (bp_extract & va eliminated)
//   5) backtrace: log-depth composition scan -> preds; + seq score -> ll
//
// ws layout (bytes):
//   pot : 0         4MB (+4KB pad)
//   (va region 4198400 unused now)
//   bp  : 8396800   1MB
//   logZ: 9445376   256B
//   last: 9445632   256B
//   maps_lse: 9445888   16MB  (4096 chunks x 1024 f32)
//   s_lse   : 26223104  16KB
//   maps_vit: 26239488  16MB
//   vb      : 43016704  512KB

#define TT 512
#define KK 32
#define HH 768
#define NB 64

#define WS_POT  0
#define WS_BP   8396800
#define WS_LOGZ 9445376
#define WS_LAST 9445632
#define WS_MLSE 9445888
#define WS_SLSE 26223104
#define WS_MVIT 26239488
#define WS_VB   43016704

// ---------------- cross-lane primitives (VALU-speed) ----------------
template <int CTRL>
__device__ __forceinline__ float dppx(float x) {
  return __int_as_float(__builtin_amdgcn_update_dpp(
      0, __float_as_int(x), CTRL, 0xF, 0xF, true));
}
__device__ __forceinline__ float xor16f(float x) {
  float d = x, s = x;
  asm volatile("v_permlane16_swap_b32 %0, %1" : "+v"(d), "+v"(s));
  return __uint_as_float(__float_as_uint(d) ^ __float_as_uint(s) ^ __float_as_uint(x));
}
__device__ __forceinline__ float xor32f(float x) {
  float d = x, s = x;
  asm volatile("v_permlane32_swap_b32 %0, %1" : "+v"(d), "+v"(s));
  return __uint_as_float(__float_as_uint(d) ^ __float_as_uint(s) ^ __float_as_uint(x));
}
__device__ __forceinline__ unsigned xor32u(unsigned x) {
  unsigned d = x, s = x;
  asm volatile("v_permlane32_swap_b32 %0, %1" : "+v"(d), "+v"(s));
  return d ^ s ^ x;
}
__device__ __forceinline__ int gmap(int m) {
  return ((m & 1) ? 1 : 0) ^ ((m & 2) ? 2 : 0) ^ ((m & 4) ? 7 : 0) ^ ((m & 8) ? 8 : 0);
}
__device__ __forceinline__ int g5(int m) { return gmap(m & 15) ^ ((m & 16) ? 16 : 0); }

#define REPL_TREE(A)                                            \
  A[1] = dppx<0xB1>(A[0]);                                      \
  _Pragma("unroll") for (int p = 0; p < 2; ++p) A[2 + p] = dppx<0x4E>(A[p]);  \
  _Pragma("unroll") for (int p = 0; p < 4; ++p) A[4 + p] = dppx<0x141>(A[p]); \
  _Pragma("unroll") for (int p = 0; p < 8; ++p) A[8 + p] = dppx<0x128>(A[p]);
#define REPL_TREE32(A)                                          \
  REPL_TREE(A)                                                  \
  _Pragma("unroll") for (int p = 0; p < 16; ++p) A[16 + p] = xor16f(A[p]);

__device__ __forceinline__ float redmax32(float v) {
  v = fmaxf(v, dppx<0xB1>(v));
  v = fmaxf(v, dppx<0x4E>(v));
  v = fmaxf(v, dppx<0x141>(v));
  v = fmaxf(v, dppx<0x128>(v));
  v = fmaxf(v, xor16f(v));
  return v;
}
__device__ __forceinline__ float redsum32(float v) {
  v += dppx<0xB1>(v);
  v += dppx<0x4E>(v);
  v += dppx<0x141>(v);
  v += dppx<0x128>(v);
  v += xor16f(v);
  return v;
}

// ---------------------------------------------------------------- GEMM ------
__global__ __launch_bounds__(256) void gemm_pot(const float* __restrict__ x,
                                                const float* __restrict__ W,
                                                const float* __restrict__ bias,
                                                float* __restrict__ pot) {
  __shared__ float4 xs4[64][16];
  __shared__ float4 wt4[32][16];
  const int tid = threadIdx.x;
  const int row0 = blockIdx.x * 64;
  const int cg = tid & 15;
  const int rg = tid >> 4;
  const int c0 = cg * 2;
  float acc[4][2] = {{0.f, 0.f}, {0.f, 0.f}, {0.f, 0.f}, {0.f, 0.f}};

  for (int h0 = 0; h0 < HH; h0 += 64) {
#pragma unroll
    for (int p = 0; p < 4; ++p) {
      const int fi = tid + p * 256;
      const int r = fi >> 4, s = fi & 15;
      const float4 v = *(const float4*)(&x[(size_t)(row0 + r) * HH + h0 + s * 4]);
      xs4[r][s ^ ((r >> 2) & 3)] = v;
    }
    {
      const int c = tid & 31;
      const int hb = (tid >> 5) * 8;
      float* wf = (float*)(&wt4[0][0]);
#pragma unroll
      for (int i2 = 0; i2 < 8; ++i2) {
        const int hh = hb + i2;
        const int slot = (hh >> 2) ^ ((c >> 1) & 15);
        wf[c * 64 + slot * 4 + (hh & 3)] = W[(size_t)(h0 + hh) * KK + c];
      }
    }
    __syncthreads();
#pragma unroll
    for (int s = 0; s < 16; ++s) {
      float4 xv[4];
#pragma unroll
      for (int i = 0; i < 4; ++i) xv[i] = xs4[rg * 4 + i][s ^ (rg & 3)];
      const float4 wv0 = wt4[c0][s ^ cg];
      const float4 wv1 = wt4[c0 + 1][s ^ cg];
#pragma unroll
      for (int i = 0; i < 4; ++i) {
        acc[i][0] += xv[i].x * wv0.x + xv[i].y * wv0.y + xv[i].z * wv0.z + xv[i].w * wv0.w;
        acc[i][1] += xv[i].x * wv1.x + xv[i].y * wv1.y + xv[i].z * wv1.z + xv[i].w * wv1.w;
      }
    }
    __syncthreads();
  }
#pragma unroll
  for (int i = 0; i < 4; ++i) {
    const int row = row0 + rg * 4 + i;
    float2 o = make_float2(acc[i][0] + bias[c0], acc[i][1] + bias[c0 + 1]);
    *(float2*)(&pot[(size_t)row * KK + c0]) = o;
  }
}

// --------------------------------------------------------------- phase A ----
// grid 1024 x 256: blocks [0,512) LSE, [512,1024) Viterbi. Block = 8
// consecutive chunks of one batch; wave = 2 chunks (32-lane halves); lane
// owns map ROW j. E staged in LDS (stride 36 f32), read uniform (broadcast).
__global__ __launch_bounds__(256, 4) void phaseA(const float* __restrict__ pot,
                                                 const int* __restrict__ lens,
                                                 const float* __restrict__ trans,
                                                 float* __restrict__ maps_lse,
                                                 float* __restrict__ scale_lse,
                                                 float* __restrict__ maps_vit) {
  __shared__ float E[32 * 36];
  __shared__ float P[64][32];
  const int tid = threadIdx.x;
  const bool is_lse = (blockIdx.x < 512);
  const int blk = is_lse ? (int)blockIdx.x : (int)blockIdx.x - 512;
  const int b = blk >> 3;
  const int c0 = (blk & 7) * 8;
  const int len = lens[b];

  // stage E (exp for LSE) and the block's 64 pot rows (exp for LSE)
  for (int i = tid; i < 1024; i += 256) {
    const float v = trans[i];
    E[(i >> 5) * 36 + (i & 31)] = is_lse ? __expf(v) : v;
  }
  for (int i = tid; i < 2048; i += 256) {
    const int r = i >> 5, kk2 = i & 31;
    int t = 8 * c0 + 1 + r;
    if (t > 511) t = 511;
    const float v = pot[((size_t)b * TT + t) * KK + kk2];
    P[r][kk2] = is_lse ? __expf(v) : v;
  }
  __syncthreads();

  const int lane = tid & 63;
  const int j = lane & 31;
  const int cc = c0 + (tid >> 6) * 2 + (lane >> 5);
  const size_t id = (size_t)b * 64 + cc;
  float* outp = (is_lse ? maps_lse : maps_vit) + id * 1024 + j * 32;
  const int t0 = 8 * cc + 1;
  const int t1 = min(8 * cc + 8, len - 1);

  float M[32];
  if (t0 > t1) {                          // dead chunk -> identity
#pragma unroll
    for (int k = 0; k < 32; ++k)
      M[k] = is_lse ? ((k == j) ? 1.f : 0.f) : ((k == j) ? 0.f : -1e30f);
    if (is_lse && j == 0) scale_lse[id] = 0.f;
  } else {
    const int lr = 8 * (cc - c0);
    // init: M = E-row-j (op) dv(t0)
#pragma unroll
    for (int q = 0; q < 8; ++q) {
      const float4 e = *(const float4*)&E[j * 36 + 4 * q];
      const float4 d = *(const float4*)&P[lr][4 * q];
      if (is_lse) {
        M[4 * q + 0] = e.x * d.x; M[4 * q + 1] = e.y * d.y;
        M[4 * q + 2] = e.z * d.z; M[4 * q + 3] = e.w * d.w;
      } else {
        M[4 * q + 0] = e.x + d.x; M[4 * q + 1] = e.y + d.y;
        M[4 * q + 2] = e.z + d.z; M[4 * q + 3] = e.w + d.w;
      }
    }
#pragma unroll 1
    for (int s = 1; s < 8; ++s) {
      const int t = t0 + s;
      if (t > t1) break;
      float acc[32];
#pragma unroll
      for (int k = 0; k < 32; ++k) acc[k] = is_lse ? 0.f : -1e30f;
#pragma unroll
      for (int mp = 0; mp < 16; ++mp) {
        const float m0 = M[2 * mp], m1 = M[2 * mp + 1];
        const float* r0 = &E[(2 * mp) * 36];
        const float* r1 = &E[(2 * mp + 1) * 36];
#pragma unroll
        for (int q = 0; q < 8; ++q) {
          const float4 e0 = *(const float4*)(r0 + 4 * q);
          const float4 e1 = *(const float4*)(r1 + 4 * q);
          if (is_lse) {
            acc[4 * q + 0] = __builtin_fmaf(m0, e0.x, acc[4 * q + 0]);
            acc[4 * q + 1] = __builtin_fmaf(m0, e0.y, acc[4 * q + 1]);
            acc[4 * q + 2] = __builtin_fmaf(m0, e0.z, acc[4 * q + 2]);
            acc[4 * q + 3] = __builtin_fmaf(m0, e0.w, acc[4 * q + 3]);
            acc[4 * q + 0] = __builtin_fmaf(m1, e1.x, acc[4 * q + 0]);
            acc[4 * q + 1] = __builtin_fmaf(m1, e1.y, acc[4 * q + 1]);
            acc[4 * q + 2] = __builtin_fmaf(m1, e1.z, acc[4 * q + 2]);
            acc[4 * q + 3] = __builtin_fmaf(m1, e1.w, acc[4 * q + 3]);
          } else {
            acc[4 * q + 0] = fmaxf(acc[4 * q + 0], fmaxf(m0 + e0.x, m1 + e1.x));
            acc[4 * q + 1] = fmaxf(acc[4 * q + 1], fmaxf(m0 + e0.y, m1 + e1.y));
            acc[4 * q + 2] = fmaxf(acc[4 * q + 2], fmaxf(m0 + e0.z, m1 + e1.z));
            acc[4 * q + 3] = fmaxf(acc[4 * q + 3], fmaxf(m0 + e0.w, m1 + e1.w));
          }
        }
        if ((mp & 3) == 3) __builtin_amdgcn_sched_barrier(0);
      }
#pragma unroll
      for (int q = 0; q < 8; ++q) {
        const float4 d = *(const float4*)&P[lr + s][4 * q];
        if (is_lse) {
          M[4 * q + 0] = acc[4 * q + 0] * d.x; M[4 * q + 1] = acc[4 * q + 1] * d.y;
          M[4 * q + 2] = acc[4 * q + 2] * d.z; M[4 * q + 3] = acc[4 * q + 3] * d.w;
        } else {
          M[4 * q + 0] = acc[4 * q + 0] + d.x; M[4 * q + 1] = acc[4 * q + 1] + d.y;
          M[4 * q + 2] = acc[4 * q + 2] + d.z; M[4 * q + 3] = acc[4 * q + 3] + d.w;
        }
      }
    }
    if (is_lse) {                         // normalize by map max
      float mx = M[0];
#pragma unroll
      for (int k = 1; k < 32; ++k) mx = fmaxf(mx, M[k]);
      mx = redmax32(mx);
      const float inv = __builtin_amdgcn_rcpf(mx);
#pragma unroll
      for (int k = 0; k < 32; ++k) M[k] *= inv;
      if (j == 0) scale_lse[id] = __logf(mx);
    }
  }
#pragma unroll
  for (int q = 0; q < 8; ++q)
    *(float4*)(outp + 4 * q) =
        make_float4(M[4 * q], M[4 * q + 1], M[4 * q + 2], M[4 * q + 3]);
}

// --------------------------------------------------------------- phase B ----
// grid 128 x 256: [0,64) LSE -> logZ; [64,128) Viterbi -> vb, last.
__global__ __launch_bounds__(256) void phaseB(const float* __restrict__ pot,
                                              const float* __restrict__ maps_lse,
                                              const float* __restrict__ scale_lse,
                                              const float* __restrict__ maps_vit,
                                              float* __restrict__ vb,
                                              float* __restrict__ logZ,
                                              int* __restrict__ last) {
  __shared__ float mbuf[2][8192];
  __shared__ float sscale;
  const int tid = threadIdx.x;
  const bool is_lse = (blockIdx.x < 64);
  const int b = is_lse ? blockIdx.x : blockIdx.x - 64;
  const float* maps = (is_lse ? maps_lse : maps_vit) + (size_t)b * 65536;

  {
    const float4* src = (const float4*)maps;
    for (int q = tid; q < 2048; q += 256) ((float4*)mbuf[0])[q] = src[q];
  }
  if (is_lse && tid == 64) {
    float s = 0.f;
#pragma unroll 8
    for (int cc = 0; cc < 64; ++cc) s += scale_lse[b * 64 + cc];
    sscale = s;
  }
  __syncthreads();

  const int k = tid;
  float aown = 0.f, alog = 0.f;
  int addr[32];
  if (tid < 32) {
#pragma unroll
    for (int m = 0; m < 32; ++m) addr[m] = ((k ^ g5(m)) << 5) + k;
    const float a0 = pot[(size_t)b * (TT * KK) + k];
    if (is_lse) {
      const float m0 = redmax32(a0);
      aown = __expf(a0 - m0);
      alog = m0;
    } else {
      aown = a0;
    }
  }

  for (int r = 0; r < 8; ++r) {
    if (r < 7 && tid >= 64) {
      const float4* src = (const float4*)(maps + (size_t)(r + 1) * 8192);
      float4* dst = (float4*)mbuf[(r + 1) & 1];
      for (int q = tid - 64; q < 2048; q += 192) dst[q] = src[q];
    }
    if (tid < 32) {
      const float* mb0 = mbuf[r & 1];
#pragma unroll 1
      for (int m2 = 0; m2 < 8; ++m2) {
        const float* mb = mb0 + m2 * 1024;
        const int cc = r * 8 + m2;
        if (!is_lse) vb[((size_t)b * 64 + cc) * 32 + k] = aown;
        float mv[32];
#pragma unroll
        for (int m = 0; m < 32; ++m) mv[m] = mb[addr[m]];
        float A[32];
        A[0] = aown;
        REPL_TREE32(A)
        if (is_lse) {
          float mxA = A[0];
#pragma unroll
          for (int m = 1; m < 32; ++m) mxA = fmaxf(mxA, A[m]);
          float s0 = 0.f, s1 = 0.f, s2 = 0.f, s3 = 0.f;
#pragma unroll
          for (int p = 0; p < 8; ++p) {
            s0 += A[4 * p + 0] * mv[4 * p + 0];
            s1 += A[4 * p + 1] * mv[4 * p + 1];
            s2 += A[4 * p + 2] * mv[4 * p + 2];
            s3 += A[4 * p + 3] * mv[4 * p + 3];
          }
          aown = ((s0 + s1) + (s2 + s3)) * __builtin_amdgcn_rcpf(mxA);
          alog += __logf(mxA);
        } else {
          float s0 = -1e30f, s1 = -1e30f, s2 = -1e30f, s3 = -1e30f;
#pragma unroll
          for (int p = 0; p < 8; ++p) {
            s0 = fmaxf(s0, A[4 * p + 0] + mv[4 * p + 0]);
            s1 = fmaxf(s1, A[4 * p + 1] + mv[4 * p + 1]);
            s2 = fmaxf(s2, A[4 * p + 2] + mv[4 * p + 2]);
            s3 = fmaxf(s3, A[4 * p + 3] + mv[4 * p + 3]);
          }
          aown = fmaxf(fmaxf(s0, s1), fmaxf(s2, s3));
        }
      }
    }
    __syncthreads();
  }
  if (tid < 32) {
    if (is_lse) {
      const float ssum = redsum32(aown);
      if (k == 0) logZ[b] = alog + __logf(ssum) + sscale;
    } else {
      float v = aown;
      int idx = k;
#pragma unroll
      for (int mm = 16; mm >= 1; mm >>= 1) {
        const float vo = __shfl_xor(v, mm, 32);
        const int io = __shfl_xor(idx, mm, 32);
        if (vo > v || (vo == v && io < idx)) { v = vo; idx = io; }
      }
      if (k == 0) last[b] = idx;
    }
  }
}

// --------------------------------------------------------------- phase C ----
// grid 1024 x 256: one chunk per wave; 8 Viterbi steps from vb; bp fused
// (mask of argmax-candidates -> lowest-index via ctz). No va materialized.
__global__ __launch_bounds__(256) void phaseC(const float* __restrict__ pot,
                                              const int* __restrict__ lens,
                                              const float* __restrict__ trans,
                                              const float* __restrict__ vb,
                                              unsigned char* __restrict__ bp) {
  const int tid = threadIdx.x;
  const int lane = tid & 63;
  const int k = lane & 31;
  const int jh = lane >> 5;
  const int id = blockIdx.x * 4 + (tid >> 6);
  const int b = id >> 6, c = id & 63;
  const int len = lens[b];
  float trx[16];
  unsigned jbit[16];
#pragma unroll
  for (int m = 0; m < 16; ++m) {
    const int jj = k ^ gmap(m) ^ (jh << 4);
    trx[m] = trans[jj * KK + k];
    jbit[m] = 1u << jj;
  }
  const float* pp = pot + (size_t)b * (TT * KK) + k;
  unsigned char* bpp = bp + (size_t)b * TT * KK + k;
  float a = vb[(size_t)id * 32 + k];
  float pb[8];
#pragma unroll
  for (int i = 0; i < 8; ++i) pb[i] = pp[(size_t)(8 * c + 1 + i) * KK];
#pragma unroll 1
  for (int s = 0; s < 8; ++s) {
    const int t = 8 * c + 1 + s;
    if (t >= len) break;
    float A[16];
    const float u16 = xor16f(a);
    A[0] = jh ? u16 : a;
    REPL_TREE(A)
    float s_[16];
#pragma unroll
    for (int m = 0; m < 16; ++m) s_[m] = A[m] + trx[m];
    const float m0 = fmaxf(fmaxf(s_[0], s_[1]), fmaxf(s_[2], s_[3]));
    const float m1 = fmaxf(fmaxf(s_[4], s_[5]), fmaxf(s_[6], s_[7]));
    const float m2 = fmaxf(fmaxf(s_[8], s_[9]), fmaxf(s_[10], s_[11]));
    const float m3 = fmaxf(fmaxf(s_[12], s_[13]), fmaxf(s_[14], s_[15]));
    const float part = fmaxf(fmaxf(m0, m1), fmaxf(m2, m3));
    const float g = fmaxf(part, xor32f(part));
    unsigned msk = 0u;
#pragma unroll
    for (int m = 0; m < 16; ++m) msk |= (s_[m] >= g) ? jbit[m] : 0u;
    msk |= xor32u(msk);
    const int bpv = __builtin_ctz(msk);     // lowest j = np.argmax tiebreak
    a = g + pb[s];
    if (lane < 32) bpp[(size_t)t * KK] = (unsigned char)bpv;
  }
}

// ------------------------------------------------------------- backtrace ----
__global__ __launch_bounds__(256) void backtrace_kernel(
    const unsigned char* __restrict__ bp, const int* __restrict__ lens,
    const int* __restrict__ last, const float* __restrict__ pot,
    const int* __restrict__ y, const float* __restrict__ trans,
    const float* __restrict__ logZ, float* __restrict__ out) {
  __shared__ unsigned char Ls[32736];
  __shared__ unsigned char sA[512], sB[512];
  __shared__ float red[256];
  const int b = blockIdx.x, tid = threadIdx.x;
  const int len = lens[b];

  for (int i = tid; i < TT * KK; i += 256) {
    const int t = i >> 5, k = i & 31;
    Ls[i] = (t >= 1 && t < len) ? bp[((size_t)b * TT + t) * KK + k] : (unsigned char)k;
  }
  __syncthreads();

  int off_prev = 0, cnt = 512;
  for (int l = 1; l <= 9; ++l) {
    const int off = 32 * (1024 - (1024 >> l));
    const int n = cnt >> 1;
    for (int i = tid; i < n * 32; i += 256) {
      const int m = i >> 5, k = i & 31;
      const int inner = Ls[off_prev + (2 * m + 1) * 32 + k];
      Ls[off + i] = Ls[off_prev + (2 * m) * 32 + inner];
    }
    __syncthreads();
    off_prev = off;
    cnt = n;
  }

  if (tid == 0) sA[0] = (unsigned char)last[b];
  __syncthreads();

  unsigned char* cur = sA;
  unsigned char* nxt = sB;
  int c2 = 1;
  for (int l = 9; l >= 1; --l) {
    const int offm = 32 * (1024 - (1024 >> (l - 1)));
    for (int i = tid; i < c2; i += 256) {
      const unsigned char s = cur[i];
      nxt[2 * i + 1] = s;
      nxt[2 * i] = Ls[offm + (2 * i + 1) * 32 + s];
    }
    __syncthreads();
    unsigned char* tmp = cur; cur = nxt; nxt = tmp;
    c2 <<= 1;
  }

  for (int t = tid; t < TT; t += 256)
    out[NB + (size_t)b * TT + t] = (t < len) ? (float)cur[t] : 0.f;

  float acc = 0.f;
  for (int t = tid; t < TT; t += 256) {
    const int yt = y[b * TT + t];
    if (t < len) acc += pot[((size_t)b * TT + t) * KK + yt];
    if (t < len - 1) acc += trans[yt * KK + y[b * TT + t + 1]];
  }
  red[tid] = acc;
  __syncthreads();
  for (int s = 128; s >= 1; s >>= 1) {
    if (tid < s) red[tid] += red[tid + s];
    __syncthreads();
  }
  if (tid == 0) out[b] = red[0] - logZ[b];
}

// ------------------------------------------------------------------ launch --
extern "C" void kernel_launch(void* const* d_in, const int* in_sizes, int n_in,
                              void* d_out, int out_size, void* d_ws, size_t ws_size,
                              hipStream_t stream) {
  const float* x = (const float*)d_in[0];
  const int* y = (const int*)d_in[1];
  const int* lens = (const int*)d_in[2];
  const float* W = (const float*)d_in[3];
  const float* bias = (const float*)d_in[4];
  const float* trans = (const float*)d_in[5];
  float* out = (float*)d_out;
  char* ws = (char*)d_ws;
  float* pot = (float*)(ws + WS_POT);
  unsigned char* bp = (unsigned char*)(ws + WS_BP);
  float* logZ = (float*)(ws + WS_LOGZ);
  int* last = (int*)(ws + WS_LAST);
  float* maps_lse = (float*)(ws + WS_MLSE);
  float* s_lse = (float*)(ws + WS_SLSE);
  float* maps_vit = (float*)(ws + WS_MVIT);
  float* vbp = (float*)(ws + WS_VB);

  gemm_pot<<<512, 256, 0, stream>>>(x, W, bias, pot);
  phaseA<<<1024, 256, 0, stream>>>(pot, lens, trans, maps_lse, s_lse, maps_vit);
  phaseB<<<128, 256, 0, stream>>>(pot, maps_lse, s_lse, maps_vit, vbp, logZ, last);
  phaseC<<<1024, 256, 0, stream>>>(pot, lens, trans, vbp, bp);
  backtrace_kernel<<<64, 256, 0, stream>>>(bp, lens, last, pot, y, trans, logZ, out);
}

// Round 15
// 153.907 us; speedup vs baseline: 3.4067x; 1.2752x over previous
//
#include <hip/hip_runtime.h>
#include <hip/hip_bf16.h>
#include <stdint.h>

// CRF entity layer: B=64, T=512, H=768, K=32
//   1) gemm_pot: pot = x·W + b
//   2) scan2:    blocks [0,64)  : linear-space LSE forward -> logZ[b]
//                blocks [64,128): Viterbi max-plus forward -> va, last[b]
//      1 batch/wave; j-split across halves; cross-lane via DPP + permlane
//      swaps (BUILTIN form — defined return pair, no asm register-aliasing
//      hazard; r5-proven: passed 153.8us absmax 0.0).
//   3) bp_extract: bp[b][t][k] = argmax_j(va[t-1][j]+trans[j][k])
//   4) backtrace: log-depth composition scan -> preds; + seq score -> ll
//
// ws layout (bytes):
//   pot : 0         4MB (+4KB pad: prefetch overshoot to t<=526)
//   va  : 4198400   4MB (+4KB pad)
//   bp  : 8396800   1MB
//   logZ: 9445376   256B
//   last: 9445632   256B

#define TT 512
#define KK 32
#define HH 768
#define NB 64

#define WS_POT 0
#define WS_VA  4198400
#define WS_BP  8396800
#define WS_LOGZ 9445376
#define WS_LAST 9445632

// ---------------- cross-lane primitives (VALU-speed) ----------------
template <int CTRL>
__device__ __forceinline__ float dppx(float x) {
  return __int_as_float(__builtin_amdgcn_update_dpp(
      0, __float_as_int(x), CTRL, 0xF, 0xF, true));
}

typedef unsigned int uint2v __attribute__((ext_vector_type(2)));

#if __has_builtin(__builtin_amdgcn_permlane16_swap)
__device__ __forceinline__ float xor16f(float x) {
  const unsigned xu = __float_as_uint(x);
  const uint2v q = __builtin_amdgcn_permlane16_swap(xu, xu, false, false);
  return __uint_as_float(q.x ^ q.y ^ xu);   // x[lane^16], direction-agnostic
}
#else
__device__ __forceinline__ float xor16f(float x) {
  return __int_as_float(__builtin_amdgcn_ds_swizzle(__float_as_int(x), 0x401F));
}
#endif

#if __has_builtin(__builtin_amdgcn_permlane32_swap)
__device__ __forceinline__ float xor32f(float x) {
  const unsigned xu = __float_as_uint(x);
  const uint2v q = __builtin_amdgcn_permlane32_swap(xu, xu, false, false);
  return __uint_as_float(q.x ^ q.y ^ xu);   // x[lane^32]
}
#else
__device__ __forceinline__ float xor32f(float x) { return __shfl_xor(x, 32, 64); }
#endif

__device__ __forceinline__ float redmax32(float v) {
  v = fmaxf(v, dppx<0xB1>(v));
  v = fmaxf(v, dppx<0x4E>(v));
  v = fmaxf(v, dppx<0x141>(v));
  v = fmaxf(v, dppx<0x128>(v));
  v = fmaxf(v, xor16f(v));
  return v;
}
__device__ __forceinline__ float redsum32(float v) {
  v += dppx<0xB1>(v);
  v += dppx<0x4E>(v);
  v += dppx<0x141>(v);
  v += dppx<0x128>(v);
  v += xor16f(v);
  return v;
}

__device__ __forceinline__ int gmap(int m) {
  return ((m & 1) ? 1 : 0) ^ ((m & 2) ? 2 : 0) ^ ((m & 4) ? 7 : 0) ^ ((m & 8) ? 8 : 0);
}

#define REPL_TREE(A)                                            \
  A[1] = dppx<0xB1>(A[0]);                                      \
  _Pragma("unroll") for (int p = 0; p < 2; ++p) A[2 + p] = dppx<0x4E>(A[p]);  \
  _Pragma("unroll") for (int p = 0; p < 4; ++p) A[4 + p] = dppx<0x141>(A[p]); \
  _Pragma("unroll") for (int p = 0; p < 8; ++p) A[8 + p] = dppx<0x128>(A[p]);

// ---------------------------------------------------------------- GEMM ------
__global__ __launch_bounds__(256) void gemm_pot(const float* __restrict__ x,
                                                const float* __restrict__ W,
                                                const float* __restrict__ bias,
                                                float* __restrict__ pot) {
  __shared__ float4 xs4[64][16];
  __shared__ float4 wt4[32][16];
  const int tid = threadIdx.x;
  const int row0 = blockIdx.x * 64;
  const int cg = tid & 15;
  const int rg = tid >> 4;
  const int c0 = cg * 2;
  float acc[4][2] = {{0.f, 0.f}, {0.f, 0.f}, {0.f, 0.f}, {0.f, 0.f}};

  for (int h0 = 0; h0 < HH; h0 += 64) {
#pragma unroll
    for (int p = 0; p < 4; ++p) {
      const int fi = tid + p * 256;
      const int r = fi >> 4, s = fi & 15;
      const float4 v = *(const float4*)(&x[(size_t)(row0 + r) * HH + h0 + s * 4]);
      xs4[r][s ^ ((r >> 2) & 3)] = v;
    }
    {
      const int c = tid & 31;
      const int hb = (tid >> 5) * 8;
      float* wf = (float*)(&wt4[0][0]);
#pragma unroll
      for (int i2 = 0; i2 < 8; ++i2) {
        const int hh = hb + i2;
        const int slot = (hh >> 2) ^ ((c >> 1) & 15);
        wf[c * 64 + slot * 4 + (hh & 3)] = W[(size_t)(h0 + hh) * KK + c];
      }
    }
    __syncthreads();
#pragma unroll
    for (int s = 0; s < 16; ++s) {
      float4 xv[4];
#pragma unroll
      for (int i = 0; i < 4; ++i) xv[i] = xs4[rg * 4 + i][s ^ (rg & 3)];
      const float4 wv0 = wt4[c0][s ^ cg];
      const float4 wv1 = wt4[c0 + 1][s ^ cg];
#pragma unroll
      for (int i = 0; i < 4; ++i) {
        acc[i][0] += xv[i].x * wv0.x + xv[i].y * wv0.y + xv[i].z * wv0.z + xv[i].w * wv0.w;
        acc[i][1] += xv[i].x * wv1.x + xv[i].y * wv1.y + xv[i].z * wv1.z + xv[i].w * wv1.w;
      }
    }
    __syncthreads();
  }
#pragma unroll
  for (int i = 0; i < 4; ++i) {
    const int row = row0 + rg * 4 + i;
    float2 o = make_float2(acc[i][0] + bias[c0], acc[i][1] + bias[c0 + 1]);
    *(float2*)(&pot[(size_t)row * KK + c0]) = o;
  }
}

// ---------------------------------------------------------------- scan2 -----
// grid 128 x 64. 1 batch per wave. lane = jh*32 + k. Half jh covers
// j = k ^ G[m] ^ (jh<<4), m=0..15.
__global__ __launch_bounds__(64) void scan2(const float* __restrict__ pot,
                                            const int* __restrict__ lens,
                                            const float* __restrict__ trans,
                                            float* __restrict__ va,
                                            float* __restrict__ logZ,
                                            int* __restrict__ last) {
  const int lane = threadIdx.x;
  const int k = lane & 31;
  const int jh = lane >> 5;
  const bool is_lse = (blockIdx.x < 64);
  const int b = is_lse ? blockIdx.x : blockIdx.x - 64;
  const int len = lens[b];
  const float* pp = pot + (size_t)b * (TT * KK) + k;

  if (is_lse) {
    // ---------- linear-space logsumexp forward ----------
    float etrx[16];
#pragma unroll
    for (int m = 0; m < 16; ++m)
      etrx[m] = __expf(trans[((k ^ gmap(m) ^ (jh << 4)) << 5) + k]);
    const float a0 = pp[0];
    const float M0 = redmax32(a0);
    float a = __expf(a0 - M0);
    float alog = M0;
    float ep[8], en[8];
#pragma unroll
    for (int i = 0; i < 8; ++i) ep[i] = __expf(pp[(size_t)(1 + i) * KK]);
    for (int tb = 1; tb < len; tb += 8) {
#pragma unroll
      for (int i = 0; i < 8; ++i) en[i] = pp[(size_t)(tb + 8 + i) * KK];
#pragma unroll
      for (int i = 0; i < 8; ++i) {
        const int t = tb + i;
        if (t >= len) break;
        float A[16];
        const float u16 = xor16f(a);
        A[0] = jh ? u16 : a;
        REPL_TREE(A)
        float d0 = 0.f, d1 = 0.f, d2 = 0.f, d3 = 0.f;
#pragma unroll
        for (int p = 0; p < 4; ++p) {
          d0 += A[4 * p + 0] * etrx[4 * p + 0];
          d1 += A[4 * p + 1] * etrx[4 * p + 1];
          d2 += A[4 * p + 2] * etrx[4 * p + 2];
          d3 += A[4 * p + 3] * etrx[4 * p + 3];
        }
        float part = (d0 + d1) + (d2 + d3);
        a = (part + xor32f(part)) * ep[i];
        if ((t & 3) == 0) {                   // renorm every 4 steps
          const float mx = redmax32(a);
          alog += __logf(mx);
          a *= (1.0f / mx);
        }
      }
#pragma unroll
      for (int i = 0; i < 8; ++i) ep[i] = __expf(en[i]);
    }
    const float ssum = redsum32(a);
    if (lane == 0) logZ[b] = alog + __logf(ssum);
  } else {
    // ---------- Viterbi max-plus forward ----------
    float trx[16];
#pragma unroll
    for (int m = 0; m < 16; ++m)
      trx[m] = trans[((k ^ gmap(m) ^ (jh << 4)) << 5) + k];
    float a = pp[0];
    float* vap = va + (size_t)b * (TT * KK) + k;
    if (lane < 32) vap[0] = a;
    float pb[8], pn[8];
#pragma unroll
    for (int i = 0; i < 8; ++i) pb[i] = pp[(size_t)(1 + i) * KK];
    for (int tb = 1; tb < len; tb += 8) {
#pragma unroll
      for (int i = 0; i < 8; ++i) pn[i] = pp[(size_t)(tb + 8 + i) * KK];
#pragma unroll
      for (int i = 0; i < 8; ++i) {
        const int t = tb + i;
        if (t >= len) break;
        float A[16];
        const float u16 = xor16f(a);
        A[0] = jh ? u16 : a;
        REPL_TREE(A)
        float s_[16];
#pragma unroll
        for (int m = 0; m < 16; ++m) s_[m] = A[m] + trx[m];
        const float m0 = fmaxf(fmaxf(s_[0], s_[1]), fmaxf(s_[2], s_[3]));
        const float m1 = fmaxf(fmaxf(s_[4], s_[5]), fmaxf(s_[6], s_[7]));
        const float m2 = fmaxf(fmaxf(s_[8], s_[9]), fmaxf(s_[10], s_[11]));
        const float m3 = fmaxf(fmaxf(s_[12], s_[13]), fmaxf(s_[14], s_[15]));
        const float part = fmaxf(fmaxf(m0, m1), fmaxf(m2, m3));
        a = fmaxf(part, xor32f(part)) + pb[i];
        if (lane < 32) vap[(size_t)t * KK] = a;
      }
#pragma unroll
      for (int i = 0; i < 8; ++i) pb[i] = pn[i];
    }
    // argmax over k (first-index tiebreak)
    float v = a;
    int idx = k;
#pragma unroll
    for (int mm = 16; mm >= 1; mm >>= 1) {
      const float vo = __shfl_xor(v, mm, 32);
      const int io = __shfl_xor(idx, mm, 32);
      if (vo > v || (vo == v && io < idx)) { v = vo; idx = io; }
    }
    if (lane == 0) last[b] = idx;
  }
}

// ----------------------------------------------------------- bp extract -----
__global__ __launch_bounds__(256) void bp_extract(const float* __restrict__ va,
                                                  const float* __restrict__ trans,
                                                  unsigned char* __restrict__ bp) {
  const int b = blockIdx.x >> 3;
  const int tbase = (blockIdx.x & 7) * 64;
  const int k = threadIdx.x & 31;
  const int ts = threadIdx.x >> 5;
  float tr[32];
#pragma unroll
  for (int j = 0; j < 32; ++j) tr[j] = trans[j * KK + k];
#pragma unroll
  for (int it = 0; it < 8; ++it) {
    const int t = tbase + it * 8 + ts;
    if (t < 1) continue;
    const float* row = va + ((size_t)b * TT + (t - 1)) * KK;
    float best = row[0] + tr[0];
    int bi = 0;
#pragma unroll
    for (int j = 1; j < 32; ++j) {
      const float s = row[j] + tr[j];
      if (s > best) { best = s; bi = j; }
    }
    bp[((size_t)b * TT + t) * KK + k] = (unsigned char)bi;
  }
}

// ------------------------------------------------------------- backtrace ----
__global__ __launch_bounds__(256) void backtrace_kernel(
    const unsigned char* __restrict__ bp, const int* __restrict__ lens,
    const int* __restrict__ last, const float* __restrict__ pot,
    const int* __restrict__ y, const float* __restrict__ trans,
    const float* __restrict__ logZ, float* __restrict__ out) {
  __shared__ unsigned char Ls[32736];
  __shared__ unsigned char sA[512], sB[512];
  __shared__ float red[256];
  const int b = blockIdx.x, tid = threadIdx.x;
  const int len = lens[b];

  for (int i = tid; i < TT * KK; i += 256) {
    const int t = i >> 5, k = i & 31;
    Ls[i] = (t >= 1 && t < len) ? bp[((size_t)b * TT + t) * KK + k] : (unsigned char)k;
  }
  __syncthreads();

  int off_prev = 0, cnt = 512;
  for (int l = 1; l <= 9; ++l) {
    const int off = 32 * (1024 - (1024 >> l));
    const int n = cnt >> 1;
    for (int i = tid; i < n * 32; i += 256) {
      const int m = i >> 5, k = i & 31;
      const int inner = Ls[off_prev + (2 * m + 1) * 32 + k];
      Ls[off + i] = Ls[off_prev + (2 * m) * 32 + inner];
    }
    __syncthreads();
    off_prev = off;
    cnt = n;
  }

  if (tid == 0) sA[0] = (unsigned char)last[b];
  __syncthreads();

  unsigned char* cur = sA;
  unsigned char* nxt = sB;
  int c2 = 1;
  for (int l = 9; l >= 1; --l) {
    const int offm = 32 * (1024 - (1024 >> (l - 1)));
    for (int i = tid; i < c2; i += 256) {
      const unsigned char s = cur[i];
      nxt[2 * i + 1] = s;
      nxt[2 * i] = Ls[offm + (2 * i + 1) * 32 + s];
    }
    __syncthreads();
    unsigned char* tmp = cur; cur = nxt; nxt = tmp;
    c2 <<= 1;
  }

  for (int t = tid; t < TT; t += 256)
    out[NB + (size_t)b * TT + t] = (t < len) ? (float)cur[t] : 0.f;

  float acc = 0.f;
  for (int t = tid; t < TT; t += 256) {
    const int yt = y[b * TT + t];
    if (t < len) acc += pot[((size_t)b * TT + t) * KK + yt];
    if (t < len - 1) acc += trans[yt * KK + y[b * TT + t + 1]];
  }
  red[tid] = acc;
  __syncthreads();
  for (int s = 128; s >= 1; s >>= 1) {
    if (tid < s) red[tid] += red[tid + s];
    __syncthreads();
  }
  if (tid == 0) out[b] = red[0] - logZ[b];
}

// ------------------------------------------------------------------ launch --
extern "C" void kernel_launch(void* const* d_in, const int* in_sizes, int n_in,
                              void* d_out, int out_size, void* d_ws, size_t ws_size,
                              hipStream_t stream) {
  const float* x = (const float*)d_in[0];
  const int* y = (const int*)d_in[1];
  const int* lens = (const int*)d_in[2];
  const float* W = (const float*)d_in[3];
  const float* bias = (const float*)d_in[4];
  const float* trans = (const float*)d_in[5];
  float* out = (float*)d_out;
  char* ws = (char*)d_ws;
  float* pot = (float*)(ws + WS_POT);
  float* va = (float*)(ws + WS_VA);
  unsigned char* bp = (unsigned char*)(ws + WS_BP);
  float* logZ = (float*)(ws + WS_LOGZ);
  int* last = (int*)(ws + WS_LAST);

  gemm_pot<<<512, 256, 0, stream>>>(x, W, bias, pot);
  scan2<<<128, 64, 0, stream>>>(pot, lens, trans, va, logZ, last);
  bp_extract<<<512, 256, 0, stream>>>(va, trans, bp);
  backtrace_kernel<<<64, 256, 0, stream>>>(bp, lens, last, pot, y, trans, logZ, out);
}